// Round 3
// baseline (2218.484 us; speedup 1.0000x reference)
//
#include <hip/hip_runtime.h>

#define HG 200
#define WGR 704
#define CC 256
#define NBOX 128

typedef unsigned short u16;
typedef __attribute__((ext_vector_type(8))) short short8;
typedef __attribute__((ext_vector_type(4))) short short4v;
typedef __attribute__((ext_vector_type(4))) float floatx4;

__device__ __forceinline__ float bf2f(u16 u) {
  unsigned int x = ((unsigned int)u) << 16;
  return __builtin_bit_cast(float, x);
}
__device__ __forceinline__ u16 f2bf(float f) {
  unsigned int x = __builtin_bit_cast(unsigned int, f);
  x += 0x7fffu + ((x >> 16) & 1u);  // round-to-nearest-even
  return (u16)(x >> 16);
}

// ---------------- weight repack + fp32->bf16: [blk][half][co][ci][kh][kw] -> [conv][tap][co][ci] ----------------
__global__ __launch_bounds__(256) void pack_w_kernel(const float* __restrict__ cw, u16* __restrict__ W2) {
  int i = blockIdx.x * 256 + threadIdx.x;  // < 6*9*256*256 = 3,538,944
  int conv = i / 589824;
  int r = i - conv * 589824;
  int tap = r / 65536;
  int r2 = r - tap * 65536;
  int co = r2 >> 8;
  int ci = r2 & 255;
  W2[i] = f2bf(cw[((conv * 256 + co) * 256 + ci) * 9 + tap]);
}

// ---------------- BN fold: inv = g/sqrt(v+eps), bias = b - m*inv ----------------
__global__ __launch_bounds__(256) void bn_prep_kernel(const float* __restrict__ g, const float* __restrict__ b,
                                                      const float* __restrict__ m, const float* __restrict__ v,
                                                      float* __restrict__ binv, float* __restrict__ bbias) {
  int i = blockIdx.x * 256 + threadIdx.x;  // < 6*256
  float inv = g[i] / sqrtf(v[i] + 1e-5f);
  binv[i] = inv;
  bbias[i] = b[i] - m[i] * inv;
}

// ---------------- box geometry: per-edge (ax, ay, vx, vy) in grid coords, f32 bit-exact ----------------
__global__ __launch_bounds__(128) void box_prep_kernel(const float* __restrict__ pb, float* __restrict__ geo) {
  int b = threadIdx.x;
  float gx[4], gy[4];
#pragma unroll
  for (int j = 0; j < 4; ++j) {
    float px = pb[(b * 8 + j) * 3 + 0];
    float py = pb[(b * 8 + j) * 3 + 1];
    gx[j] = __fdiv_rn(__fsub_rn(px, -140.8f), 0.4f);  // exact f32 ops, no contraction
    gy[j] = __fdiv_rn(__fsub_rn(py, -40.0f), 0.4f);
  }
  float* g = geo + b * 16;
#pragma unroll
  for (int e = 0; e < 4; ++e) {
    g[e * 4 + 0] = gx[e];
    g[e * 4 + 1] = gy[e];
    g[e * 4 + 2] = __fsub_rn(gx[(e + 1) & 3], gx[e]);  // vx
    g[e * 4 + 3] = __fsub_rn(gy[(e + 1) & 3], gy[e]);  // vy
  }
}

// ---------------- MLP: one block per box, all 3 layers via LDS (fp32) ----------------
__global__ __launch_bounds__(256) void mlp_kernel(
    const float* __restrict__ pb, const float* __restrict__ score,
    const float* __restrict__ w1, const float* __restrict__ b1,
    const float* __restrict__ w2, const float* __restrict__ b2,
    const float* __restrict__ w3, const float* __restrict__ b3,
    float* __restrict__ obj) {
  __shared__ float sf[25];
  __shared__ float h1[256];
  __shared__ float h2[256];
  int b = blockIdx.x, t = threadIdx.x;
  if (t < 24) sf[t] = pb[b * 24 + t];
  if (t == 24) sf[24] = score[b];
  __syncthreads();
  float a = b1[t];
  for (int k = 0; k < 25; ++k) a += sf[k] * w1[k * 256 + t];
  h1[t] = fmaxf(a, 0.0f);
  __syncthreads();
  a = b2[t];
  for (int k = 0; k < 256; ++k) a += h1[k] * w2[k * 256 + t];
  h2[t] = fmaxf(a, 0.0f);
  __syncthreads();
  a = b3[t];
  for (int k = 0; k < 256; ++k) a += h2[k] * w3[k * 256 + t];
  obj[b * 256 + t] = a * score[b];
}

// ---------------- raster (gather): one wave per cell, ballot over 128 boxes; bf16 NHWC out ----------------
__global__ __launch_bounds__(256) void raster_kernel(
    const float* __restrict__ geo, const float* __restrict__ obj, u16* __restrict__ x0) {
  __shared__ float sG[NBOX * 17];  // 16 floats/box, stride 17
  int tid = threadIdx.x;
  for (int i = tid; i < NBOX * 16; i += 256) sG[(i >> 4) * 17 + (i & 15)] = geo[i];
  __syncthreads();
  int wid = tid >> 6, lane = tid & 63;
  int cell = blockIdx.x * 4 + wid;  // 35200*4 = 140800 exactly
  int h = cell / WGR, w = cell - h * WGR;
  float cx = w + 0.5f, cy = h + 0.5f;

  // Exact f32 replica of the reference inside-test: c = vx*(cy-ay) - vy*(cx-ax); inside = all(c>=0)
  auto test = [&](int n) -> bool {
    const float* g = &sG[n * 17];
    bool ok = true;
#pragma unroll
    for (int e = 0; e < 4; ++e) {
      float ax = g[e * 4 + 0], ay = g[e * 4 + 1];
      float vx = g[e * 4 + 2], vy = g[e * 4 + 3];
      float c = __fsub_rn(__fmul_rn(vx, __fsub_rn(cy, ay)),
                          __fmul_rn(vy, __fsub_rn(cx, ax)));
      ok = ok && (c >= 0.0f);
    }
    return ok;
  };

  unsigned long long m0 = __ballot(test(lane));
  unsigned long long m1 = __ballot(test(lane + 64));
  int cnt = __popcll(m0) + __popcll(m1);
  floatx4 s = {0.f, 0.f, 0.f, 0.f};
  while (m0) { int n = __builtin_ctzll(m0); m0 &= m0 - 1; s += *(const floatx4*)(obj + n * CC + lane * 4); }
  while (m1) { int n = 64 + __builtin_ctzll(m1); m1 &= m1 - 1; s += *(const floatx4*)(obj + n * CC + lane * 4); }
  float cf = fmaxf((float)cnt, 1.0f);
  short4v o;
#pragma unroll
  for (int j = 0; j < 4; ++j) o[j] = (short)f2bf(__fdiv_rn(s[j], cf));
  *(short4v*)(x0 + cell * CC + lane * 4) = o;
}

// ---------------- conv3x3 256->256 implicit-GEMM MFMA kernel (bf16 NHWC in/out) ----------------
// Block: 256 thr = 4 waves; tile = 1 row x 64 px x 256 co; wave = 64px x 64co.
// ADD_RES: out may alias res (pixel-exact, same-thread read-before-write); in must be disjoint.
template <bool ADD_RES>
__global__ __launch_bounds__(256) void conv_kernel(
    const u16* __restrict__ in, const u16* __restrict__ wgt,
    const float* __restrict__ bninv, const float* __restrict__ bnbias,
    const u16* __restrict__ res, u16* __restrict__ out) {
  constexpr int PXS = 40;  // padded ci-chunk stride (80B = 20 banks -> <=2-way conflict, free)
  __shared__ u16 sA[3 * 66 * PXS];

  const int w0 = blockIdx.x * 64;
  const int h = blockIdx.y;
  const int tid = threadIdx.x;
  const int lane = tid & 63;
  const int wid = tid >> 6;
  const int ln15 = lane & 15;
  const int quad = lane >> 4;
  const int co_base = wid * 64;

  floatx4 acc[4][4] = {};

  for (int ck = 0; ck < 8; ++ck) {  // 8 ci-chunks of 32
    __syncthreads();
    // stage A strip: rows h-1..h+1, px w0-1..w0+64, ci ck*32..+32 (zero-fill OOB)
    for (int s = tid; s < 3 * 66 * 4; s += 256) {
      int q = s & 3;
      int p = s >> 2;
      int r = p / 66;
      int px = p - r * 66;
      int gh = h + r - 1;
      int gw = w0 + px - 1;
      short8 v = {};
      if ((unsigned)gh < (unsigned)HG && (unsigned)gw < (unsigned)WGR)
        v = *(const short8*)(in + ((gh * WGR + gw) * CC + ck * 32 + q * 8));
      *(short8*)(&sA[(r * 66 + px) * PXS + q * 8]) = v;
    }
    __syncthreads();
#pragma unroll
    for (int kh = 0; kh < 3; ++kh) {
#pragma unroll
      for (int kw = 0; kw < 3; ++kw) {
        short8 bfr[4];
#pragma unroll
        for (int nt = 0; nt < 4; ++nt) {
          int co = co_base + nt * 16 + ln15;
          bfr[nt] = *(const short8*)(wgt + ((kh * 3 + kw) * CC + co) * CC + ck * 32 + quad * 8);
        }
#pragma unroll
        for (int mt = 0; mt < 4; ++mt) {
          short8 af = *(const short8*)(&sA[(kh * 66 + mt * 16 + ln15 + kw) * PXS + quad * 8]);
#pragma unroll
          for (int nt = 0; nt < 4; ++nt)
            acc[mt][nt] = __builtin_amdgcn_mfma_f32_16x16x32_bf16(af, bfr[nt], acc[mt][nt], 0, 0, 0);
        }
      }
    }
  }

  float binv[4], bbia[4];
#pragma unroll
  for (int nt = 0; nt < 4; ++nt) {
    int co = co_base + nt * 16 + ln15;
    binv[nt] = bninv[co];
    bbia[nt] = bnbias[co];
  }

  // D layout: col(co)=lane&15, row(px)=quad*4+reg
#pragma unroll
  for (int mt = 0; mt < 4; ++mt) {
#pragma unroll
    for (int nt = 0; nt < 4; ++nt) {
      int co = co_base + nt * 16 + ln15;
#pragma unroll
      for (int r = 0; r < 4; ++r) {
        int w = w0 + mt * 16 + quad * 4 + r;
        int idx = (h * WGR + w) * CC + co;
        float v = acc[mt][nt][r] * binv[nt] + bbia[nt];
        if (ADD_RES) v += bf2f(res[idx]);
        v = fmaxf(v, 0.0f);
        out[idx] = f2bf(v);
      }
    }
  }
}

// ---------------- bf16 NHWC -> fp32 NCHW transpose (64px x 64ch tiles via LDS) ----------------
__global__ __launch_bounds__(256) void transpose_kernel(const u16* __restrict__ src, float* __restrict__ dst) {
  __shared__ u16 sT[64][68];
  int w0 = blockIdx.x * 64, h = blockIdx.y, c0 = blockIdx.z * 64;
  int tid = threadIdx.x;
  int cl = (tid & 15) * 4, wl = tid >> 4;
#pragma unroll
  for (int i = 0; i < 4; ++i) {
    int w = wl + i * 16;
    short4v v = *(const short4v*)(src + (h * WGR + w0 + w) * CC + c0 + cl);
    *(short4v*)(&sT[w][cl]) = v;
  }
  __syncthreads();
  int w4 = (tid & 15) * 4, ch = tid >> 4;
#pragma unroll
  for (int i = 0; i < 4; ++i) {
    int c = ch + i * 16;
    floatx4 v;
    v[0] = bf2f(sT[w4 + 0][c]);
    v[1] = bf2f(sT[w4 + 1][c]);
    v[2] = bf2f(sT[w4 + 2][c]);
    v[3] = bf2f(sT[w4 + 3][c]);
    *(floatx4*)(dst + (size_t)(c0 + c) * (HG * WGR) + h * WGR + w0 + w4) = v;
  }
}

extern "C" void kernel_launch(void* const* d_in, const int* in_sizes, int n_in,
                              void* d_out, int out_size, void* d_ws, size_t ws_size,
                              hipStream_t stream) {
  const float* pred_box = (const float*)d_in[0];
  const float* pred_score = (const float*)d_in[1];
  const float* w1 = (const float*)d_in[2];
  const float* b1 = (const float*)d_in[3];
  const float* w2 = (const float*)d_in[4];
  const float* b2 = (const float*)d_in[5];
  const float* w3 = (const float*)d_in[6];
  const float* b3 = (const float*)d_in[7];
  const float* conv_w = (const float*)d_in[8];
  const float* bng = (const float*)d_in[9];
  const float* bnb = (const float*)d_in[10];
  const float* bnm = (const float*)d_in[11];
  const float* bnv = (const float*)d_in[12];

  // Workspace budget: ~79.3 MB total.
  char* ws = (char*)d_ws;
  u16* W2       = (u16*)(ws);                  // 7,077,888 B packed bf16 weights
  u16* Abuf     = (u16*)(ws + 7077888);        // 72,089,600 B NHWC bf16 activations
  float* obj    = (float*)(ws + 79167488);     // 131,072 B fp32
  float* bninv  = (float*)(ws + 79298560);     // 6,144 B  [6][256]
  float* bnbias = (float*)(ws + 79304704);     // 6,144 B
  float* geo    = (float*)(ws + 79310848);     // 8,192 B  [128][16]
  // d_out is 36,044,800 floats = 144 MB; its first 72 MB doubles as the second
  // bf16 NHWC ping-pong buffer until the final transpose overwrites it with fp32.
  u16* SCR = (u16*)d_out;
  float* OUT = (float*)d_out;

  pack_w_kernel<<<13824, 256, 0, stream>>>(conv_w, W2);
  bn_prep_kernel<<<6, 256, 0, stream>>>(bng, bnb, bnm, bnv, bninv, bnbias);
  box_prep_kernel<<<1, 128, 0, stream>>>(pred_box, geo);
  mlp_kernel<<<NBOX, 256, 0, stream>>>(pred_box, pred_score, w1, b1, w2, b2, w3, b3, obj);
  raster_kernel<<<35200, 256, 0, stream>>>(geo, obj, Abuf);  // x0 -> A

  dim3 cg(11, HG);
  // block0: A -> SCR -> A (res A, in-place)
  conv_kernel<false><<<cg, 256, 0, stream>>>(Abuf, W2 + 0 * 589824, bninv + 0 * 256, bnbias + 0 * 256, nullptr, SCR);
  conv_kernel<true ><<<cg, 256, 0, stream>>>(SCR,  W2 + 1 * 589824, bninv + 1 * 256, bnbias + 1 * 256, Abuf, Abuf);
  // block1: A -> SCR -> A
  conv_kernel<false><<<cg, 256, 0, stream>>>(Abuf, W2 + 2 * 589824, bninv + 2 * 256, bnbias + 2 * 256, nullptr, SCR);
  conv_kernel<true ><<<cg, 256, 0, stream>>>(SCR,  W2 + 3 * 589824, bninv + 3 * 256, bnbias + 3 * 256, Abuf, Abuf);
  // block2: A -> SCR -> A
  conv_kernel<false><<<cg, 256, 0, stream>>>(Abuf, W2 + 4 * 589824, bninv + 4 * 256, bnbias + 4 * 256, nullptr, SCR);
  conv_kernel<true ><<<cg, 256, 0, stream>>>(SCR,  W2 + 5 * 589824, bninv + 5 * 256, bnbias + 5 * 256, Abuf, Abuf);
  // final: bf16 NHWC(A) -> fp32 NCHW(d_out)
  transpose_kernel<<<dim3(11, HG, 4), 256, 0, stream>>>(Abuf, OUT);
}

// Round 5
// 1445.327 us; speedup vs baseline: 1.5349x; 1.5349x over previous
//
#include <hip/hip_runtime.h>

#define HG 200
#define WGR 704
#define CC 256
#define NBOX 128

typedef unsigned short u16;
typedef __attribute__((ext_vector_type(8))) short short8;
typedef __attribute__((ext_vector_type(4))) short short4v;
typedef __attribute__((ext_vector_type(4))) float floatx4;

__device__ __forceinline__ float bf2f(u16 u) {
  unsigned int x = ((unsigned int)u) << 16;
  return __builtin_bit_cast(float, x);
}
__device__ __forceinline__ u16 f2bf(float f) {
  unsigned int x = __builtin_bit_cast(unsigned int, f);
  x += 0x7fffu + ((x >> 16) & 1u);  // round-to-nearest-even
  return (u16)(x >> 16);
}

// ---------------- weight repack + fp32->bf16 ----------------
// Layout: [conv][tap][ck(8)][cogrp(16)][lane(64)][8], where for lane l:
//   co = cogrp*16 + (l&15), ci = ck*32 + (l>>4)*8 + j   (j = 0..7)
// => a wave's 16co x 32ci B-fragment tile is ONE contiguous 1KB block, lane-l
//    loads at base + l*16B: perfectly coalesced global_load_dwordx4.
__global__ __launch_bounds__(256) void pack_w_kernel(const float* __restrict__ cw, u16* __restrict__ W2) {
  int i = blockIdx.x * 256 + threadIdx.x;  // < 6*9*256*256 = 3,538,944
  int conv = i / 589824;
  int r = i - conv * 589824;
  int tap = r / 65536;
  int r2 = r - tap * 65536;
  int ck = r2 >> 13;
  int r3 = r2 & 8191;
  int cogrp = r3 >> 9;
  int r4 = r3 & 511;
  int lane = r4 >> 3;
  int j = r4 & 7;
  int co = cogrp * 16 + (lane & 15);
  int ci = ck * 32 + (lane >> 4) * 8 + j;
  W2[i] = f2bf(cw[((conv * 256 + co) * 256 + ci) * 9 + tap]);
}

// ---------------- BN fold: inv = g/sqrt(v+eps), bias = b - m*inv ----------------
__global__ __launch_bounds__(256) void bn_prep_kernel(const float* __restrict__ g, const float* __restrict__ b,
                                                      const float* __restrict__ m, const float* __restrict__ v,
                                                      float* __restrict__ binv, float* __restrict__ bbias) {
  int i = blockIdx.x * 256 + threadIdx.x;  // < 6*256
  float inv = g[i] / sqrtf(v[i] + 1e-5f);
  binv[i] = inv;
  bbias[i] = b[i] - m[i] * inv;
}

// ---------------- box geometry: per-edge (ax, ay, vx, vy) in grid coords, f32 bit-exact ----------------
__global__ __launch_bounds__(128) void box_prep_kernel(const float* __restrict__ pb, float* __restrict__ geo) {
  int b = threadIdx.x;
  float gx[4], gy[4];
#pragma unroll
  for (int j = 0; j < 4; ++j) {
    float px = pb[(b * 8 + j) * 3 + 0];
    float py = pb[(b * 8 + j) * 3 + 1];
    gx[j] = __fdiv_rn(__fsub_rn(px, -140.8f), 0.4f);  // exact f32 ops, no contraction
    gy[j] = __fdiv_rn(__fsub_rn(py, -40.0f), 0.4f);
  }
  float* g = geo + b * 16;
#pragma unroll
  for (int e = 0; e < 4; ++e) {
    g[e * 4 + 0] = gx[e];
    g[e * 4 + 1] = gy[e];
    g[e * 4 + 2] = __fsub_rn(gx[(e + 1) & 3], gx[e]);  // vx
    g[e * 4 + 3] = __fsub_rn(gy[(e + 1) & 3], gy[e]);  // vy
  }
}

// ---------------- MLP: one block per box, all 3 layers via LDS (fp32) ----------------
__global__ __launch_bounds__(256) void mlp_kernel(
    const float* __restrict__ pb, const float* __restrict__ score,
    const float* __restrict__ w1, const float* __restrict__ b1,
    const float* __restrict__ w2, const float* __restrict__ b2,
    const float* __restrict__ w3, const float* __restrict__ b3,
    float* __restrict__ obj) {
  __shared__ float sf[25];
  __shared__ float h1[256];
  __shared__ float h2[256];
  int b = blockIdx.x, t = threadIdx.x;
  if (t < 24) sf[t] = pb[b * 24 + t];
  if (t == 24) sf[24] = score[b];
  __syncthreads();
  float a = b1[t];
  for (int k = 0; k < 25; ++k) a += sf[k] * w1[k * 256 + t];
  h1[t] = fmaxf(a, 0.0f);
  __syncthreads();
  a = b2[t];
  for (int k = 0; k < 256; ++k) a += h1[k] * w2[k * 256 + t];
  h2[t] = fmaxf(a, 0.0f);
  __syncthreads();
  a = b3[t];
  for (int k = 0; k < 256; ++k) a += h2[k] * w3[k * 256 + t];
  obj[b * 256 + t] = a * score[b];
}

// ---------------- raster (gather): one wave per cell, ballot over 128 boxes; bf16 NHWC out ----------------
__global__ __launch_bounds__(256) void raster_kernel(
    const float* __restrict__ geo, const float* __restrict__ obj, u16* __restrict__ x0) {
  __shared__ float sG[NBOX * 17];  // 16 floats/box, stride 17
  int tid = threadIdx.x;
  for (int i = tid; i < NBOX * 16; i += 256) sG[(i >> 4) * 17 + (i & 15)] = geo[i];
  __syncthreads();
  int wid = tid >> 6, lane = tid & 63;
  int cell = blockIdx.x * 4 + wid;  // 35200*4 = 140800 exactly
  int h = cell / WGR, w = cell - h * WGR;
  float cx = w + 0.5f, cy = h + 0.5f;

  auto test = [&](int n) -> bool {
    const float* g = &sG[n * 17];
    bool ok = true;
#pragma unroll
    for (int e = 0; e < 4; ++e) {
      float ax = g[e * 4 + 0], ay = g[e * 4 + 1];
      float vx = g[e * 4 + 2], vy = g[e * 4 + 3];
      float c = __fsub_rn(__fmul_rn(vx, __fsub_rn(cy, ay)),
                          __fmul_rn(vy, __fsub_rn(cx, ax)));
      ok = ok && (c >= 0.0f);
    }
    return ok;
  };

  unsigned long long m0 = __ballot(test(lane));
  unsigned long long m1 = __ballot(test(lane + 64));
  int cnt = __popcll(m0) + __popcll(m1);
  floatx4 s = {0.f, 0.f, 0.f, 0.f};
  while (m0) { int n = __builtin_ctzll(m0); m0 &= m0 - 1; s += *(const floatx4*)(obj + n * CC + lane * 4); }
  while (m1) { int n = 64 + __builtin_ctzll(m1); m1 &= m1 - 1; s += *(const floatx4*)(obj + n * CC + lane * 4); }
  float cf = fmaxf((float)cnt, 1.0f);
  short4v o;
#pragma unroll
  for (int j = 0; j < 4; ++j) o[j] = (short)f2bf(__fdiv_rn(s[j], cf));
  *(short4v*)(x0 + cell * CC + lane * 4) = o;
}

// ---------------- conv3x3 256->256 implicit-GEMM MFMA kernel (bf16 NHWC in/out) ----------------
// Block: 256 thr = 4 waves; tile = 2 rows x 64 px x 128 co.
// Wave (mi,ni): mi = output row within pair, ni = 64-co half; acc 4x4 of 16x16.
// A-staging register-prefetched one ci-chunk ahead to hide HBM latency.
// ADD_RES: out may alias res (same-thread read-before-write); in must be disjoint.
template <bool ADD_RES>
__global__ __launch_bounds__(256) void conv_kernel(
    const u16* __restrict__ in, const u16* __restrict__ wgt,
    const float* __restrict__ bninv, const float* __restrict__ bnbias,
    const u16* __restrict__ res, u16* __restrict__ out) {
  constexpr int PXS = 40;  // padded ci-chunk stride (80B = 20 banks)
  __shared__ u16 sA[4 * 66 * PXS];  // rows h0-1..h0+2, px w0-1..w0+64, 32 ci

  const int w0 = blockIdx.x * 64;
  const int h0 = blockIdx.y * 2;
  const int c0g = blockIdx.z * 8;  // co group base (of 16-co groups)
  const int tid = threadIdx.x;
  const int lane = tid & 63;
  const int wid = tid >> 6;
  const int ln15 = lane & 15;
  const int quad = lane >> 4;
  const int mi = wid >> 1;  // output row within pair
  const int ni = wid & 1;   // 64-co half

  // ---- precompute staging slots: 4 rows * 66 px * 4 quads = 1056 slots, 5 per thread ----
  const u16* gsrc[5];
  int ldst[5];
#pragma unroll
  for (int i = 0; i < 5; ++i) {
    int s = tid + i * 256;
    if (s < 1056) {
      int q = s & 3;
      int p = s >> 2;
      int r = p / 66;
      int px = p - r * 66;
      int gh = h0 + r - 1;
      int gw = w0 + px - 1;
      bool ok = ((unsigned)gh < (unsigned)HG) && ((unsigned)gw < (unsigned)WGR);
      gsrc[i] = ok ? (in + ((gh * WGR + gw) * CC + q * 8)) : nullptr;
      ldst[i] = (r * 66 + px) * PXS + q * 8;
    } else {
      gsrc[i] = nullptr;
      ldst[i] = -1;
    }
  }

  short8 pf[5];
  auto loadpf = [&](int ck) {
#pragma unroll
    for (int i = 0; i < 5; ++i) {
      pf[i] = short8{};
      if (gsrc[i]) pf[i] = *(const short8*)(gsrc[i] + ck * 32);
    }
  };
  auto writepf = [&]() {
#pragma unroll
    for (int i = 0; i < 5; ++i)
      if (ldst[i] >= 0) *(short8*)(&sA[ldst[i]]) = pf[i];
  };

  floatx4 acc[4][4] = {};
  loadpf(0);

  for (int ck = 0; ck < 8; ++ck) {  // 8 ci-chunks of 32
    __syncthreads();  // LDS free to overwrite
    writepf();
    __syncthreads();  // LDS ready
    if (ck < 7) loadpf(ck + 1);  // issue next chunk's HBM loads; hidden under MFMA below

#pragma unroll
    for (int kh = 0; kh < 3; ++kh) {
#pragma unroll
      for (int kw = 0; kw < 3; ++kw) {
        int tap = kh * 3 + kw;
        short8 bfr[4];
#pragma unroll
        for (int nt = 0; nt < 4; ++nt) {
          int cogrp = c0g + ni * 4 + nt;
          bfr[nt] = *(const short8*)(wgt + ((tap * 8 + ck) * 16 + cogrp) * 512 + lane * 8);
        }
#pragma unroll
        for (int mt = 0; mt < 4; ++mt) {
          short8 af = *(const short8*)(&sA[((mi + kh) * 66 + mt * 16 + ln15 + kw) * PXS + quad * 8]);
#pragma unroll
          for (int nt = 0; nt < 4; ++nt)
            acc[mt][nt] = __builtin_amdgcn_mfma_f32_16x16x32_bf16(af, bfr[nt], acc[mt][nt], 0, 0, 0);
        }
      }
    }
  }

  const int h = h0 + mi;
  float binv[4], bbia[4];
#pragma unroll
  for (int nt = 0; nt < 4; ++nt) {
    int co = (c0g + ni * 4 + nt) * 16 + ln15;
    binv[nt] = bninv[co];
    bbia[nt] = bnbias[co];
  }

  // D layout: col(co)=lane&15, row(px)=quad*4+reg
#pragma unroll
  for (int mt = 0; mt < 4; ++mt) {
#pragma unroll
    for (int nt = 0; nt < 4; ++nt) {
      int co = (c0g + ni * 4 + nt) * 16 + ln15;
#pragma unroll
      for (int r = 0; r < 4; ++r) {
        int w = w0 + mt * 16 + quad * 4 + r;
        int idx = (h * WGR + w) * CC + co;
        float v = acc[mt][nt][r] * binv[nt] + bbia[nt];
        if (ADD_RES) v += bf2f(res[idx]);
        v = fmaxf(v, 0.0f);
        out[idx] = f2bf(v);
      }
    }
  }
}

// ---------------- bf16 NHWC -> fp32 NCHW transpose (64px x 64ch tiles via LDS) ----------------
__global__ __launch_bounds__(256) void transpose_kernel(const u16* __restrict__ src, float* __restrict__ dst) {
  __shared__ u16 sT[64][68];
  int w0 = blockIdx.x * 64, h = blockIdx.y, c0 = blockIdx.z * 64;
  int tid = threadIdx.x;
  int cl = (tid & 15) * 4, wl = tid >> 4;
#pragma unroll
  for (int i = 0; i < 4; ++i) {
    int w = wl + i * 16;
    short4v v = *(const short4v*)(src + (h * WGR + w0 + w) * CC + c0 + cl);
    *(short4v*)(&sT[w][cl]) = v;
  }
  __syncthreads();
  int w4 = (tid & 15) * 4, ch = tid >> 4;
#pragma unroll
  for (int i = 0; i < 4; ++i) {
    int c = ch + i * 16;
    floatx4 v;
    v[0] = bf2f(sT[w4 + 0][c]);
    v[1] = bf2f(sT[w4 + 1][c]);
    v[2] = bf2f(sT[w4 + 2][c]);
    v[3] = bf2f(sT[w4 + 3][c]);
    *(floatx4*)(dst + (size_t)(c0 + c) * (HG * WGR) + h * WGR + w0 + w4) = v;
  }
}

extern "C" void kernel_launch(void* const* d_in, const int* in_sizes, int n_in,
                              void* d_out, int out_size, void* d_ws, size_t ws_size,
                              hipStream_t stream) {
  const float* pred_box = (const float*)d_in[0];
  const float* pred_score = (const float*)d_in[1];
  const float* w1 = (const float*)d_in[2];
  const float* b1 = (const float*)d_in[3];
  const float* w2 = (const float*)d_in[4];
  const float* b2 = (const float*)d_in[5];
  const float* w3 = (const float*)d_in[6];
  const float* b3 = (const float*)d_in[7];
  const float* conv_w = (const float*)d_in[8];
  const float* bng = (const float*)d_in[9];
  const float* bnb = (const float*)d_in[10];
  const float* bnm = (const float*)d_in[11];
  const float* bnv = (const float*)d_in[12];

  // Workspace budget: ~79.3 MB total.
  char* ws = (char*)d_ws;
  u16* W2       = (u16*)(ws);                  // 7,077,888 B packed bf16 weights
  u16* Abuf     = (u16*)(ws + 7077888);        // 72,089,600 B NHWC bf16 activations
  float* obj    = (float*)(ws + 79167488);     // 131,072 B fp32
  float* bninv  = (float*)(ws + 79298560);     // 6,144 B  [6][256]
  float* bnbias = (float*)(ws + 79304704);     // 6,144 B
  float* geo    = (float*)(ws + 79310848);     // 8,192 B  [128][16]
  // d_out (144 MB fp32): first 72 MB doubles as the second bf16 NHWC ping-pong
  // buffer until the final transpose overwrites it with fp32.
  u16* SCR = (u16*)d_out;
  float* OUT = (float*)d_out;

  pack_w_kernel<<<13824, 256, 0, stream>>>(conv_w, W2);
  bn_prep_kernel<<<6, 256, 0, stream>>>(bng, bnb, bnm, bnv, bninv, bnbias);
  box_prep_kernel<<<1, 128, 0, stream>>>(pred_box, geo);
  mlp_kernel<<<NBOX, 256, 0, stream>>>(pred_box, pred_score, w1, b1, w2, b2, w3, b3, obj);
  raster_kernel<<<35200, 256, 0, stream>>>(geo, obj, Abuf);  // x0 -> A

  dim3 cg(11, 100, 2);
  // block0: A -> SCR -> A (res A, in-place)
  conv_kernel<false><<<cg, 256, 0, stream>>>(Abuf, W2 + 0 * 589824, bninv + 0 * 256, bnbias + 0 * 256, nullptr, SCR);
  conv_kernel<true ><<<cg, 256, 0, stream>>>(SCR,  W2 + 1 * 589824, bninv + 1 * 256, bnbias + 1 * 256, Abuf, Abuf);
  // block1: A -> SCR -> A
  conv_kernel<false><<<cg, 256, 0, stream>>>(Abuf, W2 + 2 * 589824, bninv + 2 * 256, bnbias + 2 * 256, nullptr, SCR);
  conv_kernel<true ><<<cg, 256, 0, stream>>>(SCR,  W2 + 3 * 589824, bninv + 3 * 256, bnbias + 3 * 256, Abuf, Abuf);
  // block2: A -> SCR -> A
  conv_kernel<false><<<cg, 256, 0, stream>>>(Abuf, W2 + 4 * 589824, bninv + 4 * 256, bnbias + 4 * 256, nullptr, SCR);
  conv_kernel<true ><<<cg, 256, 0, stream>>>(SCR,  W2 + 5 * 589824, bninv + 5 * 256, bnbias + 5 * 256, Abuf, Abuf);
  // final: bf16 NHWC(A) -> fp32 NCHW(d_out)
  transpose_kernel<<<dim3(11, HG, 4), 256, 0, stream>>>(Abuf, OUT);
}

// Round 6
// 1405.350 us; speedup vs baseline: 1.5786x; 1.0284x over previous
//
#include <hip/hip_runtime.h>

#define HG 200
#define WGR 704
#define CC 256
#define NBOX 128

typedef unsigned short u16;
typedef __attribute__((ext_vector_type(8))) short short8;
typedef __attribute__((ext_vector_type(4))) short short4v;
typedef __attribute__((ext_vector_type(4))) float floatx4;

typedef __attribute__((address_space(1))) const unsigned int guint;
typedef __attribute__((address_space(3))) unsigned int luint;

__device__ __forceinline__ float bf2f(u16 u) {
  unsigned int x = ((unsigned int)u) << 16;
  return __builtin_bit_cast(float, x);
}
__device__ __forceinline__ u16 f2bf(float f) {
  unsigned int x = __builtin_bit_cast(unsigned int, f);
  x += 0x7fffu + ((x >> 16) & 1u);  // round-to-nearest-even
  return (u16)(x >> 16);
}

// ---------------- weight repack + fp32->bf16 ----------------
// Layout: [conv][tap][ck(8)][cogrp(16)][lane(64)][8]:
//   co = cogrp*16 + (l&15), ci = ck*32 + (l>>4)*8 + j
// => a wave's 16co x 32ci B-fragment is ONE contiguous 1KB block (lane*16B).
__global__ __launch_bounds__(256) void pack_w_kernel(const float* __restrict__ cw, u16* __restrict__ W2) {
  int i = blockIdx.x * 256 + threadIdx.x;  // < 6*9*256*256 = 3,538,944
  int conv = i / 589824;
  int r = i - conv * 589824;
  int tap = r / 65536;
  int r2 = r - tap * 65536;
  int ck = r2 >> 13;
  int r3 = r2 & 8191;
  int cogrp = r3 >> 9;
  int r4 = r3 & 511;
  int lane = r4 >> 3;
  int j = r4 & 7;
  int co = cogrp * 16 + (lane & 15);
  int ci = ck * 32 + (lane >> 4) * 8 + j;
  W2[i] = f2bf(cw[((conv * 256 + co) * 256 + ci) * 9 + tap]);
}

// ---------------- BN fold ----------------
__global__ __launch_bounds__(256) void bn_prep_kernel(const float* __restrict__ g, const float* __restrict__ b,
                                                      const float* __restrict__ m, const float* __restrict__ v,
                                                      float* __restrict__ binv, float* __restrict__ bbias) {
  int i = blockIdx.x * 256 + threadIdx.x;  // < 6*256
  float inv = g[i] / sqrtf(v[i] + 1e-5f);
  binv[i] = inv;
  bbias[i] = b[i] - m[i] * inv;
}

// ---------------- box geometry (f32 bit-exact vs reference) ----------------
__global__ __launch_bounds__(128) void box_prep_kernel(const float* __restrict__ pb, float* __restrict__ geo) {
  int b = threadIdx.x;
  float gx[4], gy[4];
#pragma unroll
  for (int j = 0; j < 4; ++j) {
    float px = pb[(b * 8 + j) * 3 + 0];
    float py = pb[(b * 8 + j) * 3 + 1];
    gx[j] = __fdiv_rn(__fsub_rn(px, -140.8f), 0.4f);
    gy[j] = __fdiv_rn(__fsub_rn(py, -40.0f), 0.4f);
  }
  float* g = geo + b * 16;
#pragma unroll
  for (int e = 0; e < 4; ++e) {
    g[e * 4 + 0] = gx[e];
    g[e * 4 + 1] = gy[e];
    g[e * 4 + 2] = __fsub_rn(gx[(e + 1) & 3], gx[e]);
    g[e * 4 + 3] = __fsub_rn(gy[(e + 1) & 3], gy[e]);
  }
}

// ---------------- MLP: one block per box ----------------
__global__ __launch_bounds__(256) void mlp_kernel(
    const float* __restrict__ pb, const float* __restrict__ score,
    const float* __restrict__ w1, const float* __restrict__ b1,
    const float* __restrict__ w2, const float* __restrict__ b2,
    const float* __restrict__ w3, const float* __restrict__ b3,
    float* __restrict__ obj) {
  __shared__ float sf[25];
  __shared__ float h1[256];
  __shared__ float h2[256];
  int b = blockIdx.x, t = threadIdx.x;
  if (t < 24) sf[t] = pb[b * 24 + t];
  if (t == 24) sf[24] = score[b];
  __syncthreads();
  float a = b1[t];
  for (int k = 0; k < 25; ++k) a += sf[k] * w1[k * 256 + t];
  h1[t] = fmaxf(a, 0.0f);
  __syncthreads();
  a = b2[t];
  for (int k = 0; k < 256; ++k) a += h1[k] * w2[k * 256 + t];
  h2[t] = fmaxf(a, 0.0f);
  __syncthreads();
  a = b3[t];
  for (int k = 0; k < 256; ++k) a += h2[k] * w3[k * 256 + t];
  obj[b * 256 + t] = a * score[b];
}

// ---------------- raster (gather): one wave per cell ----------------
__global__ __launch_bounds__(256) void raster_kernel(
    const float* __restrict__ geo, const float* __restrict__ obj, u16* __restrict__ x0) {
  __shared__ float sG[NBOX * 17];
  int tid = threadIdx.x;
  for (int i = tid; i < NBOX * 16; i += 256) sG[(i >> 4) * 17 + (i & 15)] = geo[i];
  __syncthreads();
  int wid = tid >> 6, lane = tid & 63;
  int cell = blockIdx.x * 4 + wid;  // 35200*4 = 140800
  int h = cell / WGR, w = cell - h * WGR;
  float cx = w + 0.5f, cy = h + 0.5f;

  auto test = [&](int n) -> bool {
    const float* g = &sG[n * 17];
    bool ok = true;
#pragma unroll
    for (int e = 0; e < 4; ++e) {
      float ax = g[e * 4 + 0], ay = g[e * 4 + 1];
      float vx = g[e * 4 + 2], vy = g[e * 4 + 3];
      float c = __fsub_rn(__fmul_rn(vx, __fsub_rn(cy, ay)),
                          __fmul_rn(vy, __fsub_rn(cx, ax)));
      ok = ok && (c >= 0.0f);
    }
    return ok;
  };

  unsigned long long m0 = __ballot(test(lane));
  unsigned long long m1 = __ballot(test(lane + 64));
  int cnt = __popcll(m0) + __popcll(m1);
  floatx4 s = {0.f, 0.f, 0.f, 0.f};
  while (m0) { int n = __builtin_ctzll(m0); m0 &= m0 - 1; s += *(const floatx4*)(obj + n * CC + lane * 4); }
  while (m1) { int n = 64 + __builtin_ctzll(m1); m1 &= m1 - 1; s += *(const floatx4*)(obj + n * CC + lane * 4); }
  float cf = fmaxf((float)cnt, 1.0f);
  short4v o;
#pragma unroll
  for (int j = 0; j < 4; ++j) o[j] = (short)f2bf(__fdiv_rn(s[j], cf));
  *(short4v*)(x0 + cell * CC + lane * 4) = o;
}

// ---------------- conv3x3 256->256 implicit-GEMM MFMA kernel (bf16 NHWC in/out) ----------------
// Block 256 thr = 4 waves; tile = 2 rows x 64 px x 128 co. m97-style K-loop:
// global_load_lds(16B) DMA into double-buffered LDS, ONE barrier per ci-chunk.
// LDS slot s = (r*4+q)*66+px at byte off s*16 (DMA constraint: base + lane*16).
// A-frag ds_read: lanes sequential in px -> 16B stride -> <=2-way aliasing (free).
template <bool ADD_RES>
__global__ __launch_bounds__(256, 4) void conv_kernel(
    const u16* __restrict__ in, const u16* __restrict__ wgt,
    const float* __restrict__ bninv, const float* __restrict__ bnbias,
    const u16* __restrict__ res, u16* __restrict__ out) {
  __shared__ u16 sA[2 * 1056 * 8];  // 2 x 16,896 B

  const int w0 = blockIdx.x * 64;
  const int h0 = blockIdx.y * 2;
  const int c0g = blockIdx.z * 8;  // co group base (16-co groups)
  const int tid = threadIdx.x;
  const int lane = tid & 63;
  const int wid = tid >> 6;
  const int ln15 = lane & 15;
  const int quad = lane >> 4;
  const int mi = wid >> 1;  // output row within pair
  const int ni = wid & 1;   // 64-co half

  // ---- DMA plan: 17 wave-issues of 64 slots; wave w owns issues w, w+4, w+8, w+12 (+16 for w=0).
  // slot s = I*64+lane -> r = s/264, q = (s%264)/66, px = s%66; gh = h0+r-1, gw = w0+px-1.
  const u16* ga[5];
  bool gv[5];
#pragma unroll
  for (int j = 0; j < 5; ++j) {
    int I = wid + 4 * j;
    int s = I * 64 + lane;
    int r = s / 264;
    int rem = s - r * 264;
    int q = rem / 66;
    int px = rem - q * 66;
    int gh = h0 + r - 1;
    int gw = w0 + px - 1;
    bool ok = (I <= 16) && (s < 1056) &&
              ((unsigned)gh < (unsigned)HG) && ((unsigned)gw < (unsigned)WGR);
    ga[j] = in + (gh * WGR + gw) * CC + q * 8;  // never dereferenced when !ok
    gv[j] = ok;
    // zero both buffers at geometry-invalid slots (DMA is exec-masked there; stays zero)
    if (I <= 16 && s < 1056 && !ok) {
      short8 z = {};
      *(short8*)(&sA[s * 8]) = z;
      *(short8*)(&sA[(1056 + s) * 8]) = z;
    }
  }

  auto dma = [&](int buf) {
#pragma unroll
    for (int j = 0; j < 5; ++j) {
      int I = wid + 4 * j;
      if (I <= 16) {
        u16* lp = &sA[buf * 8448 + I * 512];  // wave-uniform base; lane writes lp + lane*16B
        if (gv[j])
          __builtin_amdgcn_global_load_lds((guint*)(const void*)ga[j], (luint*)(void*)lp, 16, 0, 0);
      }
      ga[j] += 32;  // advance one ci-chunk (64 B)
    }
  };

  floatx4 acc[4][4] = {};
  dma(0);  // chunk 0 -> buf 0

  for (int ck = 0; ck < 8; ++ck) {
    const int cur = ck & 1;
    // Barrier: (a) implicit vmcnt drain => this wave's chunk-ck DMA landed; all waves past
    // barrier => whole buf[cur] valid. (b) all waves done computing ck-1 => buf[1-cur] free.
    __syncthreads();
    if (ck < 7) dma(1 - cur);  // chunk ck+1 DMA flies under the MFMA body below

    const u16* base = &sA[cur * 8448];
#pragma unroll
    for (int kh = 0; kh < 3; ++kh) {
#pragma unroll
      for (int kw = 0; kw < 3; ++kw) {
        const int tap = kh * 3 + kw;
        short8 bfr[4];
#pragma unroll
        for (int nt = 0; nt < 4; ++nt)
          bfr[nt] = *(const short8*)(wgt + (((tap * 8 + ck) * 16) + c0g + ni * 4 + nt) * 512 + lane * 8);
#pragma unroll
        for (int mt = 0; mt < 4; ++mt) {
          const int r = mi + kh;
          const int px = mt * 16 + ln15 + kw;
          short8 af = *(const short8*)(base + ((r * 4 + quad) * 66 + px) * 8);
#pragma unroll
          for (int nt = 0; nt < 4; ++nt)
            acc[mt][nt] = __builtin_amdgcn_mfma_f32_16x16x32_bf16(af, bfr[nt], acc[mt][nt], 0, 0, 0);
        }
      }
    }
  }

  const int h = h0 + mi;
  float binv[4], bbia[4];
#pragma unroll
  for (int nt = 0; nt < 4; ++nt) {
    int co = (c0g + ni * 4 + nt) * 16 + ln15;
    binv[nt] = bninv[co];
    bbia[nt] = bnbias[co];
  }

  // D layout: col(co)=lane&15, row(px)=quad*4+reg
#pragma unroll
  for (int mt = 0; mt < 4; ++mt) {
#pragma unroll
    for (int nt = 0; nt < 4; ++nt) {
      int co = (c0g + ni * 4 + nt) * 16 + ln15;
#pragma unroll
      for (int r = 0; r < 4; ++r) {
        int w = w0 + mt * 16 + quad * 4 + r;
        int idx = (h * WGR + w) * CC + co;
        float v = acc[mt][nt][r] * binv[nt] + bbia[nt];
        if (ADD_RES) v += bf2f(res[idx]);
        v = fmaxf(v, 0.0f);
        out[idx] = f2bf(v);
      }
    }
  }
}

// ---------------- bf16 NHWC -> fp32 NCHW transpose ----------------
__global__ __launch_bounds__(256) void transpose_kernel(const u16* __restrict__ src, float* __restrict__ dst) {
  __shared__ u16 sT[64][68];
  int w0 = blockIdx.x * 64, h = blockIdx.y, c0 = blockIdx.z * 64;
  int tid = threadIdx.x;
  int cl = (tid & 15) * 4, wl = tid >> 4;
#pragma unroll
  for (int i = 0; i < 4; ++i) {
    int w = wl + i * 16;
    short4v v = *(const short4v*)(src + (h * WGR + w0 + w) * CC + c0 + cl);
    *(short4v*)(&sT[w][cl]) = v;
  }
  __syncthreads();
  int w4 = (tid & 15) * 4, ch = tid >> 4;
#pragma unroll
  for (int i = 0; i < 4; ++i) {
    int c = ch + i * 16;
    floatx4 v;
    v[0] = bf2f(sT[w4 + 0][c]);
    v[1] = bf2f(sT[w4 + 1][c]);
    v[2] = bf2f(sT[w4 + 2][c]);
    v[3] = bf2f(sT[w4 + 3][c]);
    *(floatx4*)(dst + (size_t)(c0 + c) * (HG * WGR) + h * WGR + w0 + w4) = v;
  }
}

extern "C" void kernel_launch(void* const* d_in, const int* in_sizes, int n_in,
                              void* d_out, int out_size, void* d_ws, size_t ws_size,
                              hipStream_t stream) {
  const float* pred_box = (const float*)d_in[0];
  const float* pred_score = (const float*)d_in[1];
  const float* w1 = (const float*)d_in[2];
  const float* b1 = (const float*)d_in[3];
  const float* w2 = (const float*)d_in[4];
  const float* b2 = (const float*)d_in[5];
  const float* w3 = (const float*)d_in[6];
  const float* b3 = (const float*)d_in[7];
  const float* conv_w = (const float*)d_in[8];
  const float* bng = (const float*)d_in[9];
  const float* bnb = (const float*)d_in[10];
  const float* bnm = (const float*)d_in[11];
  const float* bnv = (const float*)d_in[12];

  // Workspace: ~79.3 MB total.
  char* ws = (char*)d_ws;
  u16* W2       = (u16*)(ws);                  // 7,077,888 B packed bf16 weights
  u16* Abuf     = (u16*)(ws + 7077888);        // 72,089,600 B NHWC bf16 activations
  float* obj    = (float*)(ws + 79167488);     // 131,072 B
  float* bninv  = (float*)(ws + 79298560);     // 6,144 B  [6][256]
  float* bnbias = (float*)(ws + 79304704);     // 6,144 B
  float* geo    = (float*)(ws + 79310848);     // 8,192 B  [128][16]
  // d_out (144 MB fp32): first 72 MB doubles as the second bf16 NHWC ping-pong
  // buffer until the final transpose overwrites it with fp32.
  u16* SCR = (u16*)d_out;
  float* OUT = (float*)d_out;

  pack_w_kernel<<<13824, 256, 0, stream>>>(conv_w, W2);
  bn_prep_kernel<<<6, 256, 0, stream>>>(bng, bnb, bnm, bnv, bninv, bnbias);
  box_prep_kernel<<<1, 128, 0, stream>>>(pred_box, geo);
  mlp_kernel<<<NBOX, 256, 0, stream>>>(pred_box, pred_score, w1, b1, w2, b2, w3, b3, obj);
  raster_kernel<<<35200, 256, 0, stream>>>(geo, obj, Abuf);  // x0 -> A

  dim3 cg(11, 100, 2);
  // block0: A -> SCR -> A (res A, in-place)
  conv_kernel<false><<<cg, 256, 0, stream>>>(Abuf, W2 + 0 * 589824, bninv + 0 * 256, bnbias + 0 * 256, nullptr, SCR);
  conv_kernel<true ><<<cg, 256, 0, stream>>>(SCR,  W2 + 1 * 589824, bninv + 1 * 256, bnbias + 1 * 256, Abuf, Abuf);
  // block1: A -> SCR -> A
  conv_kernel<false><<<cg, 256, 0, stream>>>(Abuf, W2 + 2 * 589824, bninv + 2 * 256, bnbias + 2 * 256, nullptr, SCR);
  conv_kernel<true ><<<cg, 256, 0, stream>>>(SCR,  W2 + 3 * 589824, bninv + 3 * 256, bnbias + 3 * 256, Abuf, Abuf);
  // block2: A -> SCR -> A
  conv_kernel<false><<<cg, 256, 0, stream>>>(Abuf, W2 + 4 * 589824, bninv + 4 * 256, bnbias + 4 * 256, nullptr, SCR);
  conv_kernel<true ><<<cg, 256, 0, stream>>>(SCR,  W2 + 5 * 589824, bninv + 5 * 256, bnbias + 5 * 256, Abuf, Abuf);
  // final: bf16 NHWC(A) -> fp32 NCHW(d_out)
  transpose_kernel<<<dim3(11, HG, 4), 256, 0, stream>>>(Abuf, OUT);
}

// Round 7
// 1193.560 us; speedup vs baseline: 1.8587x; 1.1774x over previous
//
#include <hip/hip_runtime.h>

#define HG 200
#define WGR 704
#define CC 256
#define NBOX 128

typedef unsigned short u16;
typedef __attribute__((ext_vector_type(8))) short short8;
typedef __attribute__((ext_vector_type(4))) short short4v;
typedef __attribute__((ext_vector_type(4))) float floatx4;

typedef __attribute__((address_space(1))) const unsigned int guint;
typedef __attribute__((address_space(3))) unsigned int luint;

__device__ __forceinline__ float bf2f(u16 u) {
  unsigned int x = ((unsigned int)u) << 16;
  return __builtin_bit_cast(float, x);
}
__device__ __forceinline__ u16 f2bf(float f) {
  unsigned int x = __builtin_bit_cast(unsigned int, f);
  x += 0x7fffu + ((x >> 16) & 1u);  // round-to-nearest-even
  return (u16)(x >> 16);
}

// ---------------- weight repack + fp32->bf16 ----------------
// Layout: [conv][tap][ck(8)][cogrp(16)][lane(64)][8]:
//   co = cogrp*16 + (l&15), ci = ck*32 + (l>>4)*8 + j
// => a wave's 16co x 32ci B-fragment is ONE contiguous 1KB block (lane*16B).
__global__ __launch_bounds__(256) void pack_w_kernel(const float* __restrict__ cw, u16* __restrict__ W2) {
  int i = blockIdx.x * 256 + threadIdx.x;  // < 6*9*256*256 = 3,538,944
  int conv = i / 589824;
  int r = i - conv * 589824;
  int tap = r / 65536;
  int r2 = r - tap * 65536;
  int ck = r2 >> 13;
  int r3 = r2 & 8191;
  int cogrp = r3 >> 9;
  int r4 = r3 & 511;
  int lane = r4 >> 3;
  int j = r4 & 7;
  int co = cogrp * 16 + (lane & 15);
  int ci = ck * 32 + (lane >> 4) * 8 + j;
  W2[i] = f2bf(cw[((conv * 256 + co) * 256 + ci) * 9 + tap]);
}

// ---------------- BN fold ----------------
__global__ __launch_bounds__(256) void bn_prep_kernel(const float* __restrict__ g, const float* __restrict__ b,
                                                      const float* __restrict__ m, const float* __restrict__ v,
                                                      float* __restrict__ binv, float* __restrict__ bbias) {
  int i = blockIdx.x * 256 + threadIdx.x;  // < 6*256
  float inv = g[i] / sqrtf(v[i] + 1e-5f);
  binv[i] = inv;
  bbias[i] = b[i] - m[i] * inv;
}

// ---------------- box geometry (f32 bit-exact vs reference) ----------------
__global__ __launch_bounds__(128) void box_prep_kernel(const float* __restrict__ pb, float* __restrict__ geo) {
  int b = threadIdx.x;
  float gx[4], gy[4];
#pragma unroll
  for (int j = 0; j < 4; ++j) {
    float px = pb[(b * 8 + j) * 3 + 0];
    float py = pb[(b * 8 + j) * 3 + 1];
    gx[j] = __fdiv_rn(__fsub_rn(px, -140.8f), 0.4f);
    gy[j] = __fdiv_rn(__fsub_rn(py, -40.0f), 0.4f);
  }
  float* g = geo + b * 16;
#pragma unroll
  for (int e = 0; e < 4; ++e) {
    g[e * 4 + 0] = gx[e];
    g[e * 4 + 1] = gy[e];
    g[e * 4 + 2] = __fsub_rn(gx[(e + 1) & 3], gx[e]);
    g[e * 4 + 3] = __fsub_rn(gy[(e + 1) & 3], gy[e]);
  }
}

// ---------------- MLP: one block per box ----------------
__global__ __launch_bounds__(256) void mlp_kernel(
    const float* __restrict__ pb, const float* __restrict__ score,
    const float* __restrict__ w1, const float* __restrict__ b1,
    const float* __restrict__ w2, const float* __restrict__ b2,
    const float* __restrict__ w3, const float* __restrict__ b3,
    float* __restrict__ obj) {
  __shared__ float sf[25];
  __shared__ float h1[256];
  __shared__ float h2[256];
  int b = blockIdx.x, t = threadIdx.x;
  if (t < 24) sf[t] = pb[b * 24 + t];
  if (t == 24) sf[24] = score[b];
  __syncthreads();
  float a = b1[t];
  for (int k = 0; k < 25; ++k) a += sf[k] * w1[k * 256 + t];
  h1[t] = fmaxf(a, 0.0f);
  __syncthreads();
  a = b2[t];
  for (int k = 0; k < 256; ++k) a += h1[k] * w2[k * 256 + t];
  h2[t] = fmaxf(a, 0.0f);
  __syncthreads();
  a = b3[t];
  for (int k = 0; k < 256; ++k) a += h2[k] * w3[k * 256 + t];
  obj[b * 256 + t] = a * score[b];
}

// ---------------- raster (gather): one wave per cell ----------------
__global__ __launch_bounds__(256) void raster_kernel(
    const float* __restrict__ geo, const float* __restrict__ obj, u16* __restrict__ x0) {
  __shared__ float sG[NBOX * 17];
  int tid = threadIdx.x;
  for (int i = tid; i < NBOX * 16; i += 256) sG[(i >> 4) * 17 + (i & 15)] = geo[i];
  __syncthreads();
  int wid = tid >> 6, lane = tid & 63;
  int cell = blockIdx.x * 4 + wid;  // 35200*4 = 140800
  int h = cell / WGR, w = cell - h * WGR;
  float cx = w + 0.5f, cy = h + 0.5f;

  auto test = [&](int n) -> bool {
    const float* g = &sG[n * 17];
    bool ok = true;
#pragma unroll
    for (int e = 0; e < 4; ++e) {
      float ax = g[e * 4 + 0], ay = g[e * 4 + 1];
      float vx = g[e * 4 + 2], vy = g[e * 4 + 3];
      float c = __fsub_rn(__fmul_rn(vx, __fsub_rn(cy, ay)),
                          __fmul_rn(vy, __fsub_rn(cx, ax)));
      ok = ok && (c >= 0.0f);
    }
    return ok;
  };

  unsigned long long m0 = __ballot(test(lane));
  unsigned long long m1 = __ballot(test(lane + 64));
  int cnt = __popcll(m0) + __popcll(m1);
  floatx4 s = {0.f, 0.f, 0.f, 0.f};
  while (m0) { int n = __builtin_ctzll(m0); m0 &= m0 - 1; s += *(const floatx4*)(obj + n * CC + lane * 4); }
  while (m1) { int n = 64 + __builtin_ctzll(m1); m1 &= m1 - 1; s += *(const floatx4*)(obj + n * CC + lane * 4); }
  float cf = fmaxf((float)cnt, 1.0f);
  short4v o;
#pragma unroll
  for (int j = 0; j < 4; ++j) o[j] = (short)f2bf(__fdiv_rn(s[j], cf));
  *(short4v*)(x0 + cell * CC + lane * 4) = o;
}

// ---------------- conv3x3 256->256 implicit-GEMM MFMA kernel (bf16 NHWC in/out) ----------------
// Block 256 thr = 4 waves; tile = 2 rows x 64 px x 128 co. m97-style K-loop:
// global_load_lds(16B) DMA into double-buffered LDS, ONE barrier per ci-chunk.
// B-fragments kept in a depth-3 register prefetch ring; taps 0-2 are loaded
// BEFORE the DMA issue so their vmcnt waits (FIFO) don't drain the DMA.
template <bool ADD_RES>
__global__ __launch_bounds__(256, 3) void conv_kernel(
    const u16* __restrict__ in, const u16* __restrict__ wgt,
    const float* __restrict__ bninv, const float* __restrict__ bnbias,
    const u16* __restrict__ res, u16* __restrict__ out) {
  __shared__ u16 sA[2 * 1056 * 8];  // 2 x 16,896 B

  const int w0 = blockIdx.x * 64;
  const int h0 = blockIdx.y * 2;
  const int c0g = blockIdx.z * 8;  // co group base (16-co groups)
  const int tid = threadIdx.x;
  const int lane = tid & 63;
  const int wid = tid >> 6;
  const int ln15 = lane & 15;
  const int quad = lane >> 4;
  const int mi = wid >> 1;  // output row within pair
  const int ni = wid & 1;   // 64-co half

  // ---- DMA plan: 17 wave-issues of 64 slots; wave w owns issues w, w+4, w+8, w+12 (+16 for w=0).
  // slot s = I*64+lane -> r = s/264, q = (s%264)/66, px = s%66; gh = h0+r-1, gw = w0+px-1.
  const u16* ga[5];
  bool gv[5];
#pragma unroll
  for (int j = 0; j < 5; ++j) {
    int I = wid + 4 * j;
    int s = I * 64 + lane;
    int r = s / 264;
    int rem = s - r * 264;
    int q = rem / 66;
    int px = rem - q * 66;
    int gh = h0 + r - 1;
    int gw = w0 + px - 1;
    bool ok = (I <= 16) && (s < 1056) &&
              ((unsigned)gh < (unsigned)HG) && ((unsigned)gw < (unsigned)WGR);
    ga[j] = in + (gh * WGR + gw) * CC + q * 8;  // never dereferenced when !ok
    gv[j] = ok;
    // zero both buffers at geometry-invalid slots (DMA is exec-masked there; stays zero)
    if (I <= 16 && s < 1056 && !ok) {
      short8 z = {};
      *(short8*)(&sA[s * 8]) = z;
      *(short8*)(&sA[(1056 + s) * 8]) = z;
    }
  }

  auto dma = [&](int buf) {
#pragma unroll
    for (int j = 0; j < 5; ++j) {
      int I = wid + 4 * j;
      if (I <= 16) {
        u16* lp = &sA[buf * 8448 + I * 512];  // wave-uniform base; lane writes lp + lane*16B
        if (gv[j])
          __builtin_amdgcn_global_load_lds((guint*)(const void*)ga[j], (luint*)(void*)lp, 16, 0, 0);
      }
      ga[j] += 32;  // advance one ci-chunk (64 B)
    }
  };

  // B-fragment base for this wave: cogrp set c0g+ni*4 .. +3
  const u16* wbase = wgt + ((size_t)(c0g + ni * 4)) * 512 + lane * 8;
  auto loadB = [&](int ck, int tap, short8* dst) {
#pragma unroll
    for (int nt = 0; nt < 4; ++nt)
      dst[nt] = *(const short8*)(wbase + ((tap * 8 + ck) * 16 + nt) * 512);
  };

  floatx4 acc[4][4] = {};
  short8 B[3][4];  // depth-3 prefetch ring (48 VGPRs)
  dma(0);  // chunk 0 -> buf 0

  for (int ck = 0; ck < 8; ++ck) {
    const int cur = ck & 1;
    // Barrier: (a) vmcnt drain => this wave's chunk-ck DMA landed; all waves past
    // barrier => whole buf[cur] valid. (b) all waves done with buf[1-cur].
    __syncthreads();
    // Prefetch taps 0-2's B BEFORE issuing next DMA: FIFO-older => waiting on
    // them does NOT wait for the DMA.
    loadB(ck, 0, B[0]);
    loadB(ck, 1, B[1]);
    loadB(ck, 2, B[2]);
    if (ck < 7) dma(1 - cur);  // chunk ck+1 DMA flies under the MFMA body below

    const u16* base = &sA[cur * 8448];
#pragma unroll
    for (int t = 0; t < 9; ++t) {
      const int kh = t / 3;
      const int kw = t - kh * 3;
      const short8* bc = B[t % 3];
#pragma unroll
      for (int mt = 0; mt < 4; ++mt) {
        const int r = mi + kh;
        const int px = mt * 16 + ln15 + kw;
        short8 af = *(const short8*)(base + ((r * 4 + quad) * 66 + px) * 8);
#pragma unroll
        for (int nt = 0; nt < 4; ++nt)
          acc[mt][nt] = __builtin_amdgcn_mfma_f32_16x16x32_bf16(af, bc[nt], acc[mt][nt], 0, 0, 0);
      }
      if (t + 3 < 9) loadB(ck, t + 3, B[t % 3]);  // refill consumed slot
    }
  }

  const int h = h0 + mi;
  float binv[4], bbia[4];
#pragma unroll
  for (int nt = 0; nt < 4; ++nt) {
    int co = (c0g + ni * 4 + nt) * 16 + ln15;
    binv[nt] = bninv[co];
    bbia[nt] = bnbias[co];
  }

  // D layout: col(co)=lane&15, row(px)=quad*4+reg
#pragma unroll
  for (int mt = 0; mt < 4; ++mt) {
#pragma unroll
    for (int nt = 0; nt < 4; ++nt) {
      int co = (c0g + ni * 4 + nt) * 16 + ln15;
#pragma unroll
      for (int r = 0; r < 4; ++r) {
        int w = w0 + mt * 16 + quad * 4 + r;
        int idx = (h * WGR + w) * CC + co;
        float v = acc[mt][nt][r] * binv[nt] + bbia[nt];
        if (ADD_RES) v += bf2f(res[idx]);
        v = fmaxf(v, 0.0f);
        out[idx] = f2bf(v);
      }
    }
  }
}

// ---------------- bf16 NHWC -> fp32 NCHW transpose ----------------
__global__ __launch_bounds__(256) void transpose_kernel(const u16* __restrict__ src, float* __restrict__ dst) {
  __shared__ u16 sT[64][68];
  int w0 = blockIdx.x * 64, h = blockIdx.y, c0 = blockIdx.z * 64;
  int tid = threadIdx.x;
  int cl = (tid & 15) * 4, wl = tid >> 4;
#pragma unroll
  for (int i = 0; i < 4; ++i) {
    int w = wl + i * 16;
    short4v v = *(const short4v*)(src + (h * WGR + w0 + w) * CC + c0 + cl);
    *(short4v*)(&sT[w][cl]) = v;
  }
  __syncthreads();
  int w4 = (tid & 15) * 4, ch = tid >> 4;
#pragma unroll
  for (int i = 0; i < 4; ++i) {
    int c = ch + i * 16;
    floatx4 v;
    v[0] = bf2f(sT[w4 + 0][c]);
    v[1] = bf2f(sT[w4 + 1][c]);
    v[2] = bf2f(sT[w4 + 2][c]);
    v[3] = bf2f(sT[w4 + 3][c]);
    *(floatx4*)(dst + (size_t)(c0 + c) * (HG * WGR) + h * WGR + w0 + w4) = v;
  }
}

extern "C" void kernel_launch(void* const* d_in, const int* in_sizes, int n_in,
                              void* d_out, int out_size, void* d_ws, size_t ws_size,
                              hipStream_t stream) {
  const float* pred_box = (const float*)d_in[0];
  const float* pred_score = (const float*)d_in[1];
  const float* w1 = (const float*)d_in[2];
  const float* b1 = (const float*)d_in[3];
  const float* w2 = (const float*)d_in[4];
  const float* b2 = (const float*)d_in[5];
  const float* w3 = (const float*)d_in[6];
  const float* b3 = (const float*)d_in[7];
  const float* conv_w = (const float*)d_in[8];
  const float* bng = (const float*)d_in[9];
  const float* bnb = (const float*)d_in[10];
  const float* bnm = (const float*)d_in[11];
  const float* bnv = (const float*)d_in[12];

  // Workspace: ~79.3 MB total.
  char* ws = (char*)d_ws;
  u16* W2       = (u16*)(ws);                  // 7,077,888 B packed bf16 weights
  u16* Abuf     = (u16*)(ws + 7077888);        // 72,089,600 B NHWC bf16 activations
  float* obj    = (float*)(ws + 79167488);     // 131,072 B
  float* bninv  = (float*)(ws + 79298560);     // 6,144 B  [6][256]
  float* bnbias = (float*)(ws + 79304704);     // 6,144 B
  float* geo    = (float*)(ws + 79310848);     // 8,192 B  [128][16]
  // d_out (144 MB fp32): first 72 MB doubles as the second bf16 NHWC ping-pong
  // buffer until the final transpose overwrites it with fp32.
  u16* SCR = (u16*)d_out;
  float* OUT = (float*)d_out;

  pack_w_kernel<<<13824, 256, 0, stream>>>(conv_w, W2);
  bn_prep_kernel<<<6, 256, 0, stream>>>(bng, bnb, bnm, bnv, bninv, bnbias);
  box_prep_kernel<<<1, 128, 0, stream>>>(pred_box, geo);
  mlp_kernel<<<NBOX, 256, 0, stream>>>(pred_box, pred_score, w1, b1, w2, b2, w3, b3, obj);
  raster_kernel<<<35200, 256, 0, stream>>>(geo, obj, Abuf);  // x0 -> A

  dim3 cg(11, 100, 2);
  // block0: A -> SCR -> A (res A, in-place)
  conv_kernel<false><<<cg, 256, 0, stream>>>(Abuf, W2 + 0 * 589824, bninv + 0 * 256, bnbias + 0 * 256, nullptr, SCR);
  conv_kernel<true ><<<cg, 256, 0, stream>>>(SCR,  W2 + 1 * 589824, bninv + 1 * 256, bnbias + 1 * 256, Abuf, Abuf);
  // block1: A -> SCR -> A
  conv_kernel<false><<<cg, 256, 0, stream>>>(Abuf, W2 + 2 * 589824, bninv + 2 * 256, bnbias + 2 * 256, nullptr, SCR);
  conv_kernel<true ><<<cg, 256, 0, stream>>>(SCR,  W2 + 3 * 589824, bninv + 3 * 256, bnbias + 3 * 256, Abuf, Abuf);
  // block2: A -> SCR -> A
  conv_kernel<false><<<cg, 256, 0, stream>>>(Abuf, W2 + 4 * 589824, bninv + 4 * 256, bnbias + 4 * 256, nullptr, SCR);
  conv_kernel<true ><<<cg, 256, 0, stream>>>(SCR,  W2 + 5 * 589824, bninv + 5 * 256, bnbias + 5 * 256, Abuf, Abuf);
  // final: bf16 NHWC(A) -> fp32 NCHW(d_out)
  transpose_kernel<<<dim3(11, HG, 4), 256, 0, stream>>>(Abuf, OUT);
}